// Round 13
// baseline (240.507 us; speedup 1.0000x reference)
//
#include <hip/hip_runtime.h>
#include <hip/hip_bf16.h>
#include <math.h>

// Problem constants (from reference)
#define NN 50000
#define EE 800000
#define ET 850000   // EE + NN self loops
#define NFEATS 256
#define NHIDS 32
#define NHEADS 8
#define NOUT 128

typedef __attribute__((ext_vector_type(8))) short bf16x8;
typedef __attribute__((ext_vector_type(4))) float f32x4;
typedef __attribute__((ext_vector_type(8))) unsigned short ushort8_t;

__device__ inline ushort f2bf(float x) {
    __hip_bfloat16 b = __float2bfloat16(x);   // RTN
    return *reinterpret_cast<ushort*>(&b);
}
__device__ inline float bf2f(ushort u) {
    unsigned v = ((unsigned)u) << 16;
    return __builtin_bit_cast(float, v);
}
__device__ inline float bflo(unsigned u) {
    return __builtin_bit_cast(float, u << 16);
}
__device__ inline float bfhi(unsigned u) {
    return __builtin_bit_cast(float, u & 0xffff0000u);
}

// ---------------------------------------------------------------------------
// Fused prologue: edge histogram (stores per-edge rank) + weight pre-split.
// ---------------------------------------------------------------------------
#define NW1 (256 * 256)
#define NW2 (128 * 256)
__global__ void k_prep(const int* __restrict__ ei, int* __restrict__ deg,
                       int* __restrict__ rank,
                       const float* __restrict__ W1, ushort* __restrict__ W1h,
                       ushort* __restrict__ W1l,
                       const float* __restrict__ W2, ushort* __restrict__ W2h,
                       ushort* __restrict__ W2l) {
    int i = blockIdx.x * blockDim.x + threadIdx.x;
    if (i < ET) {
        int d = (i < EE) ? ei[EE + i] : (i - EE);
        rank[i] = atomicAdd(&deg[d], 1);
    } else if (i < ET + NW1) {
        int j = i - ET;
        float v = W1[j];
        ushort h = f2bf(v);
        W1h[j] = h;
        W1l[j] = f2bf(v - bf2f(h));
    } else if (i < ET + NW1 + NW2) {
        int j = i - ET - NW1;
        float v = W2[j];
        ushort h = f2bf(v);
        W2h[j] = h;
        W2l[j] = f2bf(v - bf2f(h));
    }
}

// ---------------------------------------------------------------------------
// CSR build: scan -> scatter (rank-based; scatter also finalizes offs2)
// ---------------------------------------------------------------------------
__global__ void k_scan_block(const int* __restrict__ deg, int* __restrict__ offsets,
                             int* __restrict__ bsum, int n) {
    __shared__ int lds[1024];
    int i = blockIdx.x * 1024 + threadIdx.x;
    int v = (i < n) ? deg[i] : 0;
    lds[threadIdx.x] = v;
    __syncthreads();
    for (int off = 1; off < 1024; off <<= 1) {
        int t = 0;
        if ((int)threadIdx.x >= off) t = lds[threadIdx.x - off];
        __syncthreads();
        lds[threadIdx.x] += t;
        __syncthreads();
    }
    if (i < n) offsets[i] = lds[threadIdx.x] - v;   // exclusive within block
    if (threadIdx.x == 1023) bsum[blockIdx.x] = lds[1023];
}

__global__ void k_scan_bsums(int* __restrict__ bsum, int nb) {
    int t = threadIdx.x;                 // single block, 64 threads, nb <= 64
    int v0 = (t < nb) ? bsum[t] : 0;
    int v = v0;
    for (int off = 1; off < 64; off <<= 1) {
        int u = __shfl_up(v, off, 64);
        if (t >= off) v += u;
    }
    if (t < nb) bsum[t] = v - v0;        // exclusive block offsets
}

// Scatter (reads original offsets + bsum, no race) and finalize offs2 for agg.
__global__ void k_scatter(const int* __restrict__ ei, const int* __restrict__ offsets,
                          const int* __restrict__ bsum, const int* __restrict__ rank,
                          int* __restrict__ srcs, int* __restrict__ offs2) {
    int e = blockIdx.x * blockDim.x + threadIdx.x;
    if (e <= NN) offs2[e] = (e < NN) ? (offsets[e] + bsum[e >> 10]) : ET;
    if (e >= ET) return;
    int d, s;
    if (e < EE) { d = ei[EE + e]; s = ei[e]; }
    else        { d = e - EE;     s = e - EE; }
    srcs[offsets[d] + bsum[d >> 10] + rank[e]] = s;
}

// ---------------------------------------------------------------------------
// bf16x3 MFMA GEMM with fused attention-logit epilogue (round-7/8 VERIFIED
// fragment math). A-source: TBN==256 reads fp32 and splits in-kernel;
// TBN==128 reads pre-split hi/lo bf16 planes (pure ushort8 copies).
// ---------------------------------------------------------------------------
template <int TBN>
__global__ __launch_bounds__(512) void gemm_fused(const float* __restrict__ Af,
                                                  const ushort* __restrict__ Agh,
                                                  const ushort* __restrict__ Agl,
                                                  const ushort* __restrict__ Wh,
                                                  const ushort* __restrict__ Wl,
                                                  ushort* __restrict__ Cb,
                                                  float* __restrict__ als,
                                                  float* __restrict__ ald,
                                                  const float* __restrict__ aS,
                                                  const float* __restrict__ aD,
                                                  int M) {
    constexpr int K = 256;
    constexpr int WN = TBN / 4;    // wave n-tile: 64 or 32
    constexpr int NF = WN / 16;    // n-frags per wave: 4 or 2
    __shared__ ushort Ah[128][40], Al[128][40];
    __shared__ ushort Bh[TBN][40], Bl[TBN][40];
    __shared__ float att_red[256];

    int tid = threadIdx.x;
    int wid = tid >> 6, lane = tid & 63;
    int wm = wid >> 2, wn = wid & 3;          // 2 x 4 wave grid
    int m0 = blockIdx.x * 128;

    f32x4 acc[4][NF];
#pragma unroll
    for (int i = 0; i < 4; i++)
#pragma unroll
        for (int j = 0; j < NF; j++) acc[i][j] = (f32x4){0.f, 0.f, 0.f, 0.f};

    for (int k0 = 0; k0 < K; k0 += 32) {
        // stage A tile
        if constexpr (TBN == 256) {
            // fp32 -> hi/lo split in-kernel: 128 rows x 8 float4 = 1024 slots
#pragma unroll
            for (int i = 0; i < 2; i++) {
                int s = tid + 512 * i;
                int r = s >> 3, c4 = s & 7;
                float4 v = make_float4(0.f, 0.f, 0.f, 0.f);
                if (m0 + r < M) v = *(const float4*)(Af + (size_t)(m0 + r) * K + k0 + c4 * 4);
                ushort4 hi, lo;
                hi.x = f2bf(v.x); lo.x = f2bf(v.x - bf2f(hi.x));
                hi.y = f2bf(v.y); lo.y = f2bf(v.y - bf2f(hi.y));
                hi.z = f2bf(v.z); lo.z = f2bf(v.z - bf2f(hi.z));
                hi.w = f2bf(v.w); lo.w = f2bf(v.w - bf2f(hi.w));
                *(ushort4*)&Ah[r][c4 * 4] = hi;
                *(ushort4*)&Al[r][c4 * 4] = lo;
            }
        } else {
            // pre-split planes: 128 rows x 4 ushort8 = 512 slots = 1/thread
            int r = tid >> 2, c8 = (tid & 3) * 8;
            ushort8_t vh = {0, 0, 0, 0, 0, 0, 0, 0};
            ushort8_t vl = {0, 0, 0, 0, 0, 0, 0, 0};
            if (m0 + r < M) {
                vh = *(const ushort8_t*)(Agh + (size_t)(m0 + r) * K + k0 + c8);
                vl = *(const ushort8_t*)(Agl + (size_t)(m0 + r) * K + k0 + c8);
            }
            *(ushort8_t*)&Ah[r][c8] = vh;
            *(ushort8_t*)&Al[r][c8] = vl;
        }
        // stage B tile from pre-split planes: 16 ushorts per slot per plane
        if constexpr (TBN == 256) {
            int r = tid >> 1, c16 = (tid & 1) * 16;
            const ushort* gh = Wh + (size_t)r * K + k0 + c16;
            const ushort* gl = Wl + (size_t)r * K + k0 + c16;
            *(ushort8_t*)&Bh[r][c16]     = *(const ushort8_t*)gh;
            *(ushort8_t*)&Bh[r][c16 + 8] = *(const ushort8_t*)(gh + 8);
            *(ushort8_t*)&Bl[r][c16]     = *(const ushort8_t*)gl;
            *(ushort8_t*)&Bl[r][c16 + 8] = *(const ushort8_t*)(gl + 8);
        } else {
            int s = tid & 255;
            int r = s >> 1, c16 = (s & 1) * 16;
            const ushort* gp = ((tid < 256) ? Wh : Wl) + (size_t)r * K + k0 + c16;
            ushort* lp = ((tid < 256) ? &Bh[r][c16] : &Bl[r][c16]);
            *(ushort8_t*)lp       = *(const ushort8_t*)gp;
            *(ushort8_t*)(lp + 8) = *(const ushort8_t*)(gp + 8);
        }
        __syncthreads();

        int koff = (lane >> 4) * 8;          // k-offset within BK=32
        int rsel = lane & 15;
        bf16x8 ah[4], al[4], bh[NF], bl[NF];
#pragma unroll
        for (int mf = 0; mf < 4; mf++) {
            int r = wm * 64 + mf * 16 + rsel;
            ah[mf] = *(const bf16x8*)&Ah[r][koff];
            al[mf] = *(const bf16x8*)&Al[r][koff];
        }
#pragma unroll
        for (int nf = 0; nf < NF; nf++) {
            int c = wn * WN + nf * 16 + rsel;
            bh[nf] = *(const bf16x8*)&Bh[c][koff];
            bl[nf] = *(const bf16x8*)&Bl[c][koff];
        }
#pragma unroll
        for (int mf = 0; mf < 4; mf++)
#pragma unroll
            for (int nf = 0; nf < NF; nf++) {
                acc[mf][nf] = __builtin_amdgcn_mfma_f32_16x16x32_bf16(ah[mf], bh[nf], acc[mf][nf], 0, 0, 0);
                acc[mf][nf] = __builtin_amdgcn_mfma_f32_16x16x32_bf16(ah[mf], bl[nf], acc[mf][nf], 0, 0, 0);
                acc[mf][nf] = __builtin_amdgcn_mfma_f32_16x16x32_bf16(al[mf], bh[nf], acc[mf][nf], 0, 0, 0);
            }
        __syncthreads();
    }

    int l15 = lane & 15, lhi = lane >> 4;

    // bf16 C store (C/D layout: col = lane&15, row = (lane>>4)*4 + j)
#pragma unroll
    for (int mf = 0; mf < 4; mf++) {
        int gr0 = m0 + wm * 64 + mf * 16 + lhi * 4;
#pragma unroll
        for (int nf = 0; nf < NF; nf++) {
            int gc = wn * WN + nf * 16 + l15;
#pragma unroll
            for (int j = 0; j < 4; j++)
                if (gr0 + j < M) Cb[(size_t)(gr0 + j) * TBN + gc] = f2bf(acc[mf][nf][j]);
        }
    }

    // fused attention logits from fp32 acc
    if constexpr (TBN == 256) {
        float as0 = aS[wn * 64 + l15],      as0b = aS[wn * 64 + 16 + l15];
        float as1 = aS[wn * 64 + 32 + l15], as1b = aS[wn * 64 + 48 + l15];
        float ad0 = aD[wn * 64 + l15],      ad0b = aD[wn * 64 + 16 + l15];
        float ad1 = aD[wn * 64 + 32 + l15], ad1b = aD[wn * 64 + 48 + l15];
#pragma unroll
        for (int mf = 0; mf < 4; mf++) {
#pragma unroll
            for (int j = 0; j < 4; j++) {
                float ps0 = acc[mf][0][j] * as0 + acc[mf][1][j] * as0b;
                float ps1 = acc[mf][2][j] * as1 + acc[mf][3][j] * as1b;
                float pd0 = acc[mf][0][j] * ad0 + acc[mf][1][j] * ad0b;
                float pd1 = acc[mf][2][j] * ad1 + acc[mf][3][j] * ad1b;
#pragma unroll
                for (int off = 1; off <= 8; off <<= 1) {
                    ps0 += __shfl_xor(ps0, off, 64);
                    ps1 += __shfl_xor(ps1, off, 64);
                    pd0 += __shfl_xor(pd0, off, 64);
                    pd1 += __shfl_xor(pd1, off, 64);
                }
                int gr = m0 + wm * 64 + mf * 16 + lhi * 4 + j;
                if (l15 == 0 && gr < M) {
                    als[gr * 8 + 2 * wn]     = ps0;
                    als[gr * 8 + 2 * wn + 1] = ps1;
                    ald[gr * 8 + 2 * wn]     = pd0;
                    ald[gr * 8 + 2 * wn + 1] = pd1;
                }
            }
        }
    } else {
        // single head over 128 cols; cross-wave reduce via LDS
        float asv0 = aS[wn * 32 + l15], asv1 = aS[wn * 32 + 16 + l15];
        float adv0 = aD[wn * 32 + l15], adv1 = aD[wn * 32 + 16 + l15];
        if (tid < 256) att_red[tid] = 0.f;
        __syncthreads();
#pragma unroll
        for (int mf = 0; mf < 4; mf++) {
#pragma unroll
            for (int j = 0; j < 4; j++) {
                float ps = acc[mf][0][j] * asv0 + acc[mf][1][j] * asv1;
                float pd = acc[mf][0][j] * adv0 + acc[mf][1][j] * adv1;
#pragma unroll
                for (int off = 1; off <= 8; off <<= 1) {
                    ps += __shfl_xor(ps, off, 64);
                    pd += __shfl_xor(pd, off, 64);
                }
                if (l15 == 0) {
                    int rl = wm * 64 + mf * 16 + lhi * 4 + j;
                    atomicAdd(&att_red[rl], ps);
                    atomicAdd(&att_red[128 + rl], pd);
                }
            }
        }
        __syncthreads();
        if (tid < 128 && m0 + tid < M) {
            als[m0 + tid] = att_red[tid];
            ald[m0 + tid] = att_red[128 + tid];
        }
    }
}

// ---------------------------------------------------------------------------
// Layer 1 aggregation v2 (round-8 VERIFIED wave body): now 256 thr = 4 waves
// = 4 nodes/block (per-wave code identical; halves workgroup count).
// Epilogue writes pre-split hi/lo bf16 planes (round-12 verified).
// ---------------------------------------------------------------------------
__global__ __launch_bounds__(256) void k_agg1(
    const ushort* __restrict__ h1b, const float* __restrict__ als,
    const float* __restrict__ ald, const int* __restrict__ offsets,
    const int* __restrict__ srcs, const float* __restrict__ b1,
    ushort* __restrict__ out1h, ushort* __restrict__ out1l) {
    int lane = threadIdx.x & 63;
    int wv = threadIdx.x >> 6;        // 0..3
    int n = blockIdx.x * 4 + wv;
    int g = lane >> 5;                // edge parity slot (0/1)
    int c32 = lane & 31;              // 16B slot within row: comps [8*c32, 8*c32+8)
    int head = c32 >> 2;              // head of owned comps
    int base = offsets[n], deg = offsets[n + 1] - base;

    int eL8 = lane >> 3;              // staged edge 0..7
    int hS = lane & 7;                // staged head
    float aldS = ald[n * 8 + hS];

    float acc[8] = {0.f, 0.f, 0.f, 0.f, 0.f, 0.f, 0.f, 0.f};
    float dsum = 0.f;
    for (int chunk = 0; chunk < deg; chunk += 16) {
        int len = deg - chunk; if (len > 16) len = 16;
        int i0 = chunk + eL8;     if (i0 >= deg) i0 = deg - 1;
        int i1 = chunk + 8 + eL8; if (i1 >= deg) i1 = deg - 1;
        int sE0 = srcs[base + i0];
        int sE1 = srcs[base + i1];
        float v0 = als[sE0 * 8 + hS] + aldS;
        float v1 = als[sE1 * 8 + hS] + aldS;
        v0 = (v0 >= 0.f) ? v0 : 0.2f * v0;
        v1 = (v1 >= 0.f) ? v1 : 0.2f * v1;
        float w0 = __expf(v0), w1 = __expf(v1);
#pragma unroll
        for (int i = 0; i < 8; i++) {
            int e = 2 * i + g;                     // 0..15
            int slot = (e & 7) * 8;                // staging lane group base
            int si = __shfl((i < 4) ? sE0 : sE1, slot, 64);
            float wi = __shfl((i < 4) ? w0 : w1, slot + head, 64);
            if (e >= len) wi = 0.f;                // mask dummy edges
            uint4 hv = *(const uint4*)(h1b + (size_t)si * 256 + 8 * c32);
            acc[0] += wi * bflo(hv.x); acc[1] += wi * bfhi(hv.x);
            acc[2] += wi * bflo(hv.y); acc[3] += wi * bfhi(hv.y);
            acc[4] += wi * bflo(hv.z); acc[5] += wi * bfhi(hv.z);
            acc[6] += wi * bflo(hv.w); acc[7] += wi * bfhi(hv.w);
            dsum += wi;
        }
    }
    // combine the two half-wave edge streams
#pragma unroll
    for (int j = 0; j < 8; j++) acc[j] += __shfl_xor(acc[j], 32, 64);
    dsum += __shfl_xor(dsum, 32, 64);

    if (g == 0) {
        float inv = 1.f / (dsum + 1e-16f);
        const float* bb = b1 + 8 * c32;
        ushort8_t vh, vl;
#pragma unroll
        for (int j = 0; j < 8; j++) {
            float t = acc[j] * inv + bb[j];
            float r = (t >= 0.f) ? t : 0.2f * t;   // module LeakyReLU
            ushort h = f2bf(r);
            vh[j] = h;
            vl[j] = f2bf(r - bf2f(h));
        }
        *(ushort8_t*)(out1h + (size_t)n * 256 + 8 * c32) = vh;
        *(ushort8_t*)(out1l + (size_t)n * 256 + 8 * c32) = vl;
    }
}

// ---------------------------------------------------------------------------
// Layer 2 aggregation v2 (round-8 VERIFIED wave body): 256 thr = 4 waves =
// 4 nodes/block.
// ---------------------------------------------------------------------------
__global__ __launch_bounds__(256) void k_agg2(
    const ushort* __restrict__ h2b, const float* __restrict__ als,
    const float* __restrict__ ald, const int* __restrict__ offsets,
    const int* __restrict__ srcs, const float* __restrict__ b2,
    float* __restrict__ out) {
    int lane = threadIdx.x & 63;
    int wv = threadIdx.x >> 6;        // 0..3
    int n = blockIdx.x * 4 + wv;
    int g = lane >> 4;                // edge slot (0..3)
    int c16 = lane & 15;              // 16B slot within row: comps [8*c16, 8*c16+8)
    int base = offsets[n], deg = offsets[n + 1] - base;
    float aldv = ald[n];

    float acc[8] = {0.f, 0.f, 0.f, 0.f, 0.f, 0.f, 0.f, 0.f};
    float dsum = 0.f;
    for (int chunk = 0; chunk < deg; chunk += 16) {
        int len = deg - chunk; if (len > 16) len = 16;
        int idx = chunk + c16; if (idx >= deg) idx = deg - 1;
        int sE = srcs[base + idx];
        float v = als[sE] + aldv;
        v = (v >= 0.f) ? v : 0.2f * v;
        float wE = __expf(v);
#pragma unroll
        for (int i = 0; i < 4; i++) {
            int e = 4 * i + g;                     // 0..15
            int si = __shfl(sE, e, 64);
            float wi = __shfl(wE, e, 64);
            if (e >= len) wi = 0.f;
            uint4 hv = *(const uint4*)(h2b + (size_t)si * 128 + 8 * c16);
            acc[0] += wi * bflo(hv.x); acc[1] += wi * bfhi(hv.x);
            acc[2] += wi * bflo(hv.y); acc[3] += wi * bfhi(hv.y);
            acc[4] += wi * bflo(hv.z); acc[5] += wi * bfhi(hv.z);
            acc[6] += wi * bflo(hv.w); acc[7] += wi * bfhi(hv.w);
            dsum += wi;
        }
    }
    // combine the four quarter-wave edge streams
#pragma unroll
    for (int j = 0; j < 8; j++) {
        acc[j] += __shfl_xor(acc[j], 16, 64);
        acc[j] += __shfl_xor(acc[j], 32, 64);
    }
    dsum += __shfl_xor(dsum, 16, 64);
    dsum += __shfl_xor(dsum, 32, 64);

    if (g == 0) {
        float inv = 1.f / (dsum + 1e-16f);
        const float* bb = b2 + 8 * c16;
        float r[8];
#pragma unroll
        for (int j = 0; j < 8; j++) r[j] = acc[j] * inv + bb[j];
        float* o = out + (size_t)n * 128 + 8 * c16;
        *(float4*)o       = make_float4(r[0], r[1], r[2], r[3]);
        *(float4*)(o + 4) = make_float4(r[4], r[5], r[6], r[7]);
    }
}

// ---------------------------------------------------------------------------
extern "C" void kernel_launch(void* const* d_in, const int* in_sizes, int n_in,
                              void* d_out, int out_size, void* d_ws, size_t ws_size,
                              hipStream_t stream) {
    const int* ei = (const int*)d_in[0];         // [2, EE] int32
    const float* x = (const float*)d_in[1];      // [N, 256]
    const float* W1 = (const float*)d_in[2];     // [256, 256]
    const float* aS1 = (const float*)d_in[3];    // [8, 32]
    const float* aD1 = (const float*)d_in[4];    // [8, 32]
    const float* b1 = (const float*)d_in[5];     // [256]
    const float* W2 = (const float*)d_in[6];     // [128, 256]
    const float* aS2 = (const float*)d_in[7];    // [1, 128]
    const float* aD2 = (const float*)d_in[8];    // [1, 128]
    const float* b2 = (const float*)d_in[9];     // [128]
    float* out = (float*)d_out;

    char* w = (char*)d_ws;
    auto alloc = [&](size_t bytes) {
        char* p = w;
        w += (bytes + 255) & ~(size_t)255;
        return p;
    };
    ushort* h1b   = (ushort*)alloc((size_t)NN * 256 * 2);  // reused as h2b
    ushort* out1h = (ushort*)alloc((size_t)NN * 256 * 2);
    ushort* out1l = (ushort*)alloc((size_t)NN * 256 * 2);
    float*  als1  = (float*)alloc((size_t)NN * 8 * 4);     // reused as als2
    float*  ald1  = (float*)alloc((size_t)NN * 8 * 4);     // reused as ald2
    int* deg     = (int*)alloc((size_t)(NN + 1) * 4);
    int* offsets = (int*)alloc((size_t)(NN + 1) * 4);
    int* offs2   = (int*)alloc((size_t)(NN + 1) * 4);
    int* rank    = (int*)alloc((size_t)ET * 4);
    int* srcs    = (int*)alloc((size_t)ET * 4);
    int* bsum    = (int*)alloc(64 * 4);
    ushort* W1h  = (ushort*)alloc((size_t)NW1 * 2);
    ushort* W1l  = (ushort*)alloc((size_t)NW1 * 2);
    ushort* W2h  = (ushort*)alloc((size_t)NW2 * 2);
    ushort* W2l  = (ushort*)alloc((size_t)NW2 * 2);
    ushort* h2b = h1b;
    float* als2 = als1;
    float* ald2 = ald1;

    const int nb = (NN + 1023) / 1024;

    hipMemsetAsync(deg, 0, (size_t)NN * 4, stream);

    // fused prologue: histogram (rank-storing) + weight pre-split
    const int prep_total = ET + NW1 + NW2;
    k_prep<<<(prep_total + 255) / 256, 256, 0, stream>>>(ei, deg, rank, W1, W1h, W1l, W2, W2h, W2l);

    // CSR build (scatter also finalizes offs2)
    k_scan_block<<<nb, 1024, 0, stream>>>(deg, offsets, bsum, NN);
    k_scan_bsums<<<1, 64, 0, stream>>>(bsum, nb);
    k_scatter<<<(ET + 255) / 256, 256, 0, stream>>>(ei, offsets, bsum, rank, srcs, offs2);

    // Layer 1: GEMM + fused logits (128-row tiles), then aggregate
    gemm_fused<256><<<(NN + 127) / 128, 512, 0, stream>>>(x, nullptr, nullptr, W1h, W1l, h1b, als1, ald1, aS1, aD1, NN);
    k_agg1<<<NN / 4, 256, 0, stream>>>(h1b, als1, ald1, offs2, srcs, b1, out1h, out1l);

    // Layer 2: GEMM (pre-split A) + fused logits, then aggregate
    gemm_fused<128><<<(NN + 127) / 128, 512, 0, stream>>>(nullptr, out1h, out1l, W2h, W2l, h2b, als2, ald2, aS2, aD2, NN);
    k_agg2<<<NN / 4, 256, 0, stream>>>(h2b, als2, ald2, offs2, srcs, b2, out);
}

// Round 14
// 238.154 us; speedup vs baseline: 1.0099x; 1.0099x over previous
//
#include <hip/hip_runtime.h>
#include <hip/hip_bf16.h>
#include <math.h>

// Problem constants (from reference)
#define NN 50000
#define EE 800000
#define ET 850000   // EE + NN self loops
#define NFEATS 256
#define NHIDS 32
#define NHEADS 8
#define NOUT 128

typedef __attribute__((ext_vector_type(8))) short bf16x8;
typedef __attribute__((ext_vector_type(4))) float f32x4;
typedef __attribute__((ext_vector_type(8))) unsigned short ushort8_t;

__device__ inline ushort f2bf(float x) {
    __hip_bfloat16 b = __float2bfloat16(x);   // RTN
    return *reinterpret_cast<ushort*>(&b);
}
__device__ inline float bf2f(ushort u) {
    unsigned v = ((unsigned)u) << 16;
    return __builtin_bit_cast(float, v);
}
__device__ inline float bflo(unsigned u) {
    return __builtin_bit_cast(float, u << 16);
}
__device__ inline float bfhi(unsigned u) {
    return __builtin_bit_cast(float, u & 0xffff0000u);
}

// ---------------------------------------------------------------------------
// Fused prologue: edge histogram (stores per-edge rank) + weight pre-split.
// ---------------------------------------------------------------------------
#define NW1 (256 * 256)
#define NW2 (128 * 256)
__global__ void k_prep(const int* __restrict__ ei, int* __restrict__ deg,
                       int* __restrict__ rank,
                       const float* __restrict__ W1, ushort* __restrict__ W1h,
                       ushort* __restrict__ W1l,
                       const float* __restrict__ W2, ushort* __restrict__ W2h,
                       ushort* __restrict__ W2l) {
    int i = blockIdx.x * blockDim.x + threadIdx.x;
    if (i < ET) {
        int d = (i < EE) ? ei[EE + i] : (i - EE);
        rank[i] = atomicAdd(&deg[d], 1);
    } else if (i < ET + NW1) {
        int j = i - ET;
        float v = W1[j];
        ushort h = f2bf(v);
        W1h[j] = h;
        W1l[j] = f2bf(v - bf2f(h));
    } else if (i < ET + NW1 + NW2) {
        int j = i - ET - NW1;
        float v = W2[j];
        ushort h = f2bf(v);
        W2h[j] = h;
        W2l[j] = f2bf(v - bf2f(h));
    }
}

// ---------------------------------------------------------------------------
// CSR build: scan -> scatter (rank-based; scatter also finalizes offs2)
// ---------------------------------------------------------------------------
__global__ void k_scan_block(const int* __restrict__ deg, int* __restrict__ offsets,
                             int* __restrict__ bsum, int n) {
    __shared__ int lds[1024];
    int i = blockIdx.x * 1024 + threadIdx.x;
    int v = (i < n) ? deg[i] : 0;
    lds[threadIdx.x] = v;
    __syncthreads();
    for (int off = 1; off < 1024; off <<= 1) {
        int t = 0;
        if ((int)threadIdx.x >= off) t = lds[threadIdx.x - off];
        __syncthreads();
        lds[threadIdx.x] += t;
        __syncthreads();
    }
    if (i < n) offsets[i] = lds[threadIdx.x] - v;   // exclusive within block
    if (threadIdx.x == 1023) bsum[blockIdx.x] = lds[1023];
}

__global__ void k_scan_bsums(int* __restrict__ bsum, int nb) {
    int t = threadIdx.x;                 // single block, 64 threads, nb <= 64
    int v0 = (t < nb) ? bsum[t] : 0;
    int v = v0;
    for (int off = 1; off < 64; off <<= 1) {
        int u = __shfl_up(v, off, 64);
        if (t >= off) v += u;
    }
    if (t < nb) bsum[t] = v - v0;        // exclusive block offsets
}

// Scatter (reads original offsets + bsum, no race) and finalize offs2 for agg.
__global__ void k_scatter(const int* __restrict__ ei, const int* __restrict__ offsets,
                          const int* __restrict__ bsum, const int* __restrict__ rank,
                          int* __restrict__ srcs, int* __restrict__ offs2) {
    int e = blockIdx.x * blockDim.x + threadIdx.x;
    if (e <= NN) offs2[e] = (e < NN) ? (offsets[e] + bsum[e >> 10]) : ET;
    if (e >= ET) return;
    int d, s;
    if (e < EE) { d = ei[EE + e]; s = ei[e]; }
    else        { d = e - EE;     s = e - EE; }
    srcs[offsets[d] + bsum[d >> 10] + rank[e]] = s;
}

// ---------------------------------------------------------------------------
// bf16x3 MFMA GEMM with fused attention-logit epilogue (round-7/8 VERIFIED
// fragment math). A-source: TBN==256 reads fp32 and splits in-kernel;
// TBN==128 reads pre-split hi/lo bf16 planes (pure ushort8 copies).
// ---------------------------------------------------------------------------
template <int TBN>
__global__ __launch_bounds__(512) void gemm_fused(const float* __restrict__ Af,
                                                  const ushort* __restrict__ Agh,
                                                  const ushort* __restrict__ Agl,
                                                  const ushort* __restrict__ Wh,
                                                  const ushort* __restrict__ Wl,
                                                  ushort* __restrict__ Cb,
                                                  float* __restrict__ als,
                                                  float* __restrict__ ald,
                                                  const float* __restrict__ aS,
                                                  const float* __restrict__ aD,
                                                  int M) {
    constexpr int K = 256;
    constexpr int WN = TBN / 4;    // wave n-tile: 64 or 32
    constexpr int NF = WN / 16;    // n-frags per wave: 4 or 2
    __shared__ ushort Ah[128][40], Al[128][40];
    __shared__ ushort Bh[TBN][40], Bl[TBN][40];
    __shared__ float att_red[256];

    int tid = threadIdx.x;
    int wid = tid >> 6, lane = tid & 63;
    int wm = wid >> 2, wn = wid & 3;          // 2 x 4 wave grid
    int m0 = blockIdx.x * 128;

    f32x4 acc[4][NF];
#pragma unroll
    for (int i = 0; i < 4; i++)
#pragma unroll
        for (int j = 0; j < NF; j++) acc[i][j] = (f32x4){0.f, 0.f, 0.f, 0.f};

    for (int k0 = 0; k0 < K; k0 += 32) {
        // stage A tile
        if constexpr (TBN == 256) {
            // fp32 -> hi/lo split in-kernel: 128 rows x 8 float4 = 1024 slots
#pragma unroll
            for (int i = 0; i < 2; i++) {
                int s = tid + 512 * i;
                int r = s >> 3, c4 = s & 7;
                float4 v = make_float4(0.f, 0.f, 0.f, 0.f);
                if (m0 + r < M) v = *(const float4*)(Af + (size_t)(m0 + r) * K + k0 + c4 * 4);
                ushort4 hi, lo;
                hi.x = f2bf(v.x); lo.x = f2bf(v.x - bf2f(hi.x));
                hi.y = f2bf(v.y); lo.y = f2bf(v.y - bf2f(hi.y));
                hi.z = f2bf(v.z); lo.z = f2bf(v.z - bf2f(hi.z));
                hi.w = f2bf(v.w); lo.w = f2bf(v.w - bf2f(hi.w));
                *(ushort4*)&Ah[r][c4 * 4] = hi;
                *(ushort4*)&Al[r][c4 * 4] = lo;
            }
        } else {
            // pre-split planes: 128 rows x 4 ushort8 = 512 slots = 1/thread
            int r = tid >> 2, c8 = (tid & 3) * 8;
            ushort8_t vh = {0, 0, 0, 0, 0, 0, 0, 0};
            ushort8_t vl = {0, 0, 0, 0, 0, 0, 0, 0};
            if (m0 + r < M) {
                vh = *(const ushort8_t*)(Agh + (size_t)(m0 + r) * K + k0 + c8);
                vl = *(const ushort8_t*)(Agl + (size_t)(m0 + r) * K + k0 + c8);
            }
            *(ushort8_t*)&Ah[r][c8] = vh;
            *(ushort8_t*)&Al[r][c8] = vl;
        }
        // stage B tile from pre-split planes: 16 ushorts per slot per plane
        if constexpr (TBN == 256) {
            int r = tid >> 1, c16 = (tid & 1) * 16;
            const ushort* gh = Wh + (size_t)r * K + k0 + c16;
            const ushort* gl = Wl + (size_t)r * K + k0 + c16;
            *(ushort8_t*)&Bh[r][c16]     = *(const ushort8_t*)gh;
            *(ushort8_t*)&Bh[r][c16 + 8] = *(const ushort8_t*)(gh + 8);
            *(ushort8_t*)&Bl[r][c16]     = *(const ushort8_t*)gl;
            *(ushort8_t*)&Bl[r][c16 + 8] = *(const ushort8_t*)(gl + 8);
        } else {
            int s = tid & 255;
            int r = s >> 1, c16 = (s & 1) * 16;
            const ushort* gp = ((tid < 256) ? Wh : Wl) + (size_t)r * K + k0 + c16;
            ushort* lp = ((tid < 256) ? &Bh[r][c16] : &Bl[r][c16]);
            *(ushort8_t*)lp       = *(const ushort8_t*)gp;
            *(ushort8_t*)(lp + 8) = *(const ushort8_t*)(gp + 8);
        }
        __syncthreads();

        int koff = (lane >> 4) * 8;          // k-offset within BK=32
        int rsel = lane & 15;
        bf16x8 ah[4], al[4], bh[NF], bl[NF];
#pragma unroll
        for (int mf = 0; mf < 4; mf++) {
            int r = wm * 64 + mf * 16 + rsel;
            ah[mf] = *(const bf16x8*)&Ah[r][koff];
            al[mf] = *(const bf16x8*)&Al[r][koff];
        }
#pragma unroll
        for (int nf = 0; nf < NF; nf++) {
            int c = wn * WN + nf * 16 + rsel;
            bh[nf] = *(const bf16x8*)&Bh[c][koff];
            bl[nf] = *(const bf16x8*)&Bl[c][koff];
        }
#pragma unroll
        for (int mf = 0; mf < 4; mf++)
#pragma unroll
            for (int nf = 0; nf < NF; nf++) {
                acc[mf][nf] = __builtin_amdgcn_mfma_f32_16x16x32_bf16(ah[mf], bh[nf], acc[mf][nf], 0, 0, 0);
                acc[mf][nf] = __builtin_amdgcn_mfma_f32_16x16x32_bf16(ah[mf], bl[nf], acc[mf][nf], 0, 0, 0);
                acc[mf][nf] = __builtin_amdgcn_mfma_f32_16x16x32_bf16(al[mf], bh[nf], acc[mf][nf], 0, 0, 0);
            }
        __syncthreads();
    }

    int l15 = lane & 15, lhi = lane >> 4;

    // bf16 C store (C/D layout: col = lane&15, row = (lane>>4)*4 + j)
#pragma unroll
    for (int mf = 0; mf < 4; mf++) {
        int gr0 = m0 + wm * 64 + mf * 16 + lhi * 4;
#pragma unroll
        for (int nf = 0; nf < NF; nf++) {
            int gc = wn * WN + nf * 16 + l15;
#pragma unroll
            for (int j = 0; j < 4; j++)
                if (gr0 + j < M) Cb[(size_t)(gr0 + j) * TBN + gc] = f2bf(acc[mf][nf][j]);
        }
    }

    // fused attention logits from fp32 acc
    if constexpr (TBN == 256) {
        float as0 = aS[wn * 64 + l15],      as0b = aS[wn * 64 + 16 + l15];
        float as1 = aS[wn * 64 + 32 + l15], as1b = aS[wn * 64 + 48 + l15];
        float ad0 = aD[wn * 64 + l15],      ad0b = aD[wn * 64 + 16 + l15];
        float ad1 = aD[wn * 64 + 32 + l15], ad1b = aD[wn * 64 + 48 + l15];
#pragma unroll
        for (int mf = 0; mf < 4; mf++) {
#pragma unroll
            for (int j = 0; j < 4; j++) {
                float ps0 = acc[mf][0][j] * as0 + acc[mf][1][j] * as0b;
                float ps1 = acc[mf][2][j] * as1 + acc[mf][3][j] * as1b;
                float pd0 = acc[mf][0][j] * ad0 + acc[mf][1][j] * ad0b;
                float pd1 = acc[mf][2][j] * ad1 + acc[mf][3][j] * ad1b;
#pragma unroll
                for (int off = 1; off <= 8; off <<= 1) {
                    ps0 += __shfl_xor(ps0, off, 64);
                    ps1 += __shfl_xor(ps1, off, 64);
                    pd0 += __shfl_xor(pd0, off, 64);
                    pd1 += __shfl_xor(pd1, off, 64);
                }
                int gr = m0 + wm * 64 + mf * 16 + lhi * 4 + j;
                if (l15 == 0 && gr < M) {
                    als[gr * 8 + 2 * wn]     = ps0;
                    als[gr * 8 + 2 * wn + 1] = ps1;
                    ald[gr * 8 + 2 * wn]     = pd0;
                    ald[gr * 8 + 2 * wn + 1] = pd1;
                }
            }
        }
    } else {
        // single head over 128 cols; cross-wave reduce via LDS
        float asv0 = aS[wn * 32 + l15], asv1 = aS[wn * 32 + 16 + l15];
        float adv0 = aD[wn * 32 + l15], adv1 = aD[wn * 32 + 16 + l15];
        if (tid < 256) att_red[tid] = 0.f;
        __syncthreads();
#pragma unroll
        for (int mf = 0; mf < 4; mf++) {
#pragma unroll
            for (int j = 0; j < 4; j++) {
                float ps = acc[mf][0][j] * asv0 + acc[mf][1][j] * asv1;
                float pd = acc[mf][0][j] * adv0 + acc[mf][1][j] * adv1;
#pragma unroll
                for (int off = 1; off <= 8; off <<= 1) {
                    ps += __shfl_xor(ps, off, 64);
                    pd += __shfl_xor(pd, off, 64);
                }
                if (l15 == 0) {
                    int rl = wm * 64 + mf * 16 + lhi * 4 + j;
                    atomicAdd(&att_red[rl], ps);
                    atomicAdd(&att_red[128 + rl], pd);
                }
            }
        }
        __syncthreads();
        if (tid < 128 && m0 + tid < M) {
            als[m0 + tid] = att_red[tid];
            ald[m0 + tid] = att_red[128 + tid];
        }
    }
}

// ---------------------------------------------------------------------------
// Layer 1 aggregation v2 (round-12 VERIFIED config): 128 thr = 2 waves =
// 2 nodes/block; 16B gathers; 16-edge chunk, uniform body. Epilogue writes
// pre-split hi/lo bf16 planes.
// ---------------------------------------------------------------------------
__global__ __launch_bounds__(128) void k_agg1(
    const ushort* __restrict__ h1b, const float* __restrict__ als,
    const float* __restrict__ ald, const int* __restrict__ offsets,
    const int* __restrict__ srcs, const float* __restrict__ b1,
    ushort* __restrict__ out1h, ushort* __restrict__ out1l) {
    int lane = threadIdx.x & 63;
    int wv = threadIdx.x >> 6;
    int n = blockIdx.x * 2 + wv;
    int g = lane >> 5;                // edge parity slot (0/1)
    int c32 = lane & 31;              // 16B slot within row: comps [8*c32, 8*c32+8)
    int head = c32 >> 2;              // head of owned comps
    int base = offsets[n], deg = offsets[n + 1] - base;

    int eL8 = lane >> 3;              // staged edge 0..7
    int hS = lane & 7;                // staged head
    float aldS = ald[n * 8 + hS];

    float acc[8] = {0.f, 0.f, 0.f, 0.f, 0.f, 0.f, 0.f, 0.f};
    float dsum = 0.f;
    for (int chunk = 0; chunk < deg; chunk += 16) {
        int len = deg - chunk; if (len > 16) len = 16;
        int i0 = chunk + eL8;     if (i0 >= deg) i0 = deg - 1;
        int i1 = chunk + 8 + eL8; if (i1 >= deg) i1 = deg - 1;
        int sE0 = srcs[base + i0];
        int sE1 = srcs[base + i1];
        float v0 = als[sE0 * 8 + hS] + aldS;
        float v1 = als[sE1 * 8 + hS] + aldS;
        v0 = (v0 >= 0.f) ? v0 : 0.2f * v0;
        v1 = (v1 >= 0.f) ? v1 : 0.2f * v1;
        float w0 = __expf(v0), w1 = __expf(v1);
#pragma unroll
        for (int i = 0; i < 8; i++) {
            int e = 2 * i + g;                     // 0..15
            int slot = (e & 7) * 8;                // staging lane group base
            int si = __shfl((i < 4) ? sE0 : sE1, slot, 64);
            float wi = __shfl((i < 4) ? w0 : w1, slot + head, 64);
            if (e >= len) wi = 0.f;                // mask dummy edges
            uint4 hv = *(const uint4*)(h1b + (size_t)si * 256 + 8 * c32);
            acc[0] += wi * bflo(hv.x); acc[1] += wi * bfhi(hv.x);
            acc[2] += wi * bflo(hv.y); acc[3] += wi * bfhi(hv.y);
            acc[4] += wi * bflo(hv.z); acc[5] += wi * bfhi(hv.z);
            acc[6] += wi * bflo(hv.w); acc[7] += wi * bfhi(hv.w);
            dsum += wi;
        }
    }
    // combine the two half-wave edge streams
#pragma unroll
    for (int j = 0; j < 8; j++) acc[j] += __shfl_xor(acc[j], 32, 64);
    dsum += __shfl_xor(dsum, 32, 64);

    if (g == 0) {
        float inv = 1.f / (dsum + 1e-16f);
        const float* bb = b1 + 8 * c32;
        ushort8_t vh, vl;
#pragma unroll
        for (int j = 0; j < 8; j++) {
            float t = acc[j] * inv + bb[j];
            float r = (t >= 0.f) ? t : 0.2f * t;   // module LeakyReLU
            ushort h = f2bf(r);
            vh[j] = h;
            vl[j] = f2bf(r - bf2f(h));
        }
        *(ushort8_t*)(out1h + (size_t)n * 256 + 8 * c32) = vh;
        *(ushort8_t*)(out1l + (size_t)n * 256 + 8 * c32) = vl;
    }
}

// ---------------------------------------------------------------------------
// Layer 2 aggregation v2 (round-12 VERIFIED config): 128 thr = 2 waves =
// 2 nodes/block; 16B gathers; 16-edge chunk, uniform body.
// ---------------------------------------------------------------------------
__global__ __launch_bounds__(128) void k_agg2(
    const ushort* __restrict__ h2b, const float* __restrict__ als,
    const float* __restrict__ ald, const int* __restrict__ offsets,
    const int* __restrict__ srcs, const float* __restrict__ b2,
    float* __restrict__ out) {
    int lane = threadIdx.x & 63;
    int wv = threadIdx.x >> 6;
    int n = blockIdx.x * 2 + wv;
    int g = lane >> 4;                // edge slot (0..3)
    int c16 = lane & 15;              // 16B slot within row: comps [8*c16, 8*c16+8)
    int base = offsets[n], deg = offsets[n + 1] - base;
    float aldv = ald[n];

    float acc[8] = {0.f, 0.f, 0.f, 0.f, 0.f, 0.f, 0.f, 0.f};
    float dsum = 0.f;
    for (int chunk = 0; chunk < deg; chunk += 16) {
        int len = deg - chunk; if (len > 16) len = 16;
        int idx = chunk + c16; if (idx >= deg) idx = deg - 1;
        int sE = srcs[base + idx];
        float v = als[sE] + aldv;
        v = (v >= 0.f) ? v : 0.2f * v;
        float wE = __expf(v);
#pragma unroll
        for (int i = 0; i < 4; i++) {
            int e = 4 * i + g;                     // 0..15
            int si = __shfl(sE, e, 64);
            float wi = __shfl(wE, e, 64);
            if (e >= len) wi = 0.f;
            uint4 hv = *(const uint4*)(h2b + (size_t)si * 128 + 8 * c16);
            acc[0] += wi * bflo(hv.x); acc[1] += wi * bfhi(hv.x);
            acc[2] += wi * bflo(hv.y); acc[3] += wi * bfhi(hv.y);
            acc[4] += wi * bflo(hv.z); acc[5] += wi * bfhi(hv.z);
            acc[6] += wi * bflo(hv.w); acc[7] += wi * bfhi(hv.w);
            dsum += wi;
        }
    }
    // combine the four quarter-wave edge streams
#pragma unroll
    for (int j = 0; j < 8; j++) {
        acc[j] += __shfl_xor(acc[j], 16, 64);
        acc[j] += __shfl_xor(acc[j], 32, 64);
    }
    dsum += __shfl_xor(dsum, 16, 64);
    dsum += __shfl_xor(dsum, 32, 64);

    if (g == 0) {
        float inv = 1.f / (dsum + 1e-16f);
        const float* bb = b2 + 8 * c16;
        float r[8];
#pragma unroll
        for (int j = 0; j < 8; j++) r[j] = acc[j] * inv + bb[j];
        float* o = out + (size_t)n * 128 + 8 * c16;
        *(float4*)o       = make_float4(r[0], r[1], r[2], r[3]);
        *(float4*)(o + 4) = make_float4(r[4], r[5], r[6], r[7]);
    }
}

// ---------------------------------------------------------------------------
extern "C" void kernel_launch(void* const* d_in, const int* in_sizes, int n_in,
                              void* d_out, int out_size, void* d_ws, size_t ws_size,
                              hipStream_t stream) {
    const int* ei = (const int*)d_in[0];         // [2, EE] int32
    const float* x = (const float*)d_in[1];      // [N, 256]
    const float* W1 = (const float*)d_in[2];     // [256, 256]
    const float* aS1 = (const float*)d_in[3];    // [8, 32]
    const float* aD1 = (const float*)d_in[4];    // [8, 32]
    const float* b1 = (const float*)d_in[5];     // [256]
    const float* W2 = (const float*)d_in[6];     // [128, 256]
    const float* aS2 = (const float*)d_in[7];    // [1, 128]
    const float* aD2 = (const float*)d_in[8];    // [1, 128]
    const float* b2 = (const float*)d_in[9];     // [128]
    float* out = (float*)d_out;

    char* w = (char*)d_ws;
    auto alloc = [&](size_t bytes) {
        char* p = w;
        w += (bytes + 255) & ~(size_t)255;
        return p;
    };
    ushort* h1b   = (ushort*)alloc((size_t)NN * 256 * 2);  // reused as h2b
    ushort* out1h = (ushort*)alloc((size_t)NN * 256 * 2);
    ushort* out1l = (ushort*)alloc((size_t)NN * 256 * 2);
    float*  als1  = (float*)alloc((size_t)NN * 8 * 4);     // reused as als2
    float*  ald1  = (float*)alloc((size_t)NN * 8 * 4);     // reused as ald2
    int* deg     = (int*)alloc((size_t)(NN + 1) * 4);
    int* offsets = (int*)alloc((size_t)(NN + 1) * 4);
    int* offs2   = (int*)alloc((size_t)(NN + 1) * 4);
    int* rank    = (int*)alloc((size_t)ET * 4);
    int* srcs    = (int*)alloc((size_t)ET * 4);
    int* bsum    = (int*)alloc(64 * 4);
    ushort* W1h  = (ushort*)alloc((size_t)NW1 * 2);
    ushort* W1l  = (ushort*)alloc((size_t)NW1 * 2);
    ushort* W2h  = (ushort*)alloc((size_t)NW2 * 2);
    ushort* W2l  = (ushort*)alloc((size_t)NW2 * 2);
    ushort* h2b = h1b;
    float* als2 = als1;
    float* ald2 = ald1;

    const int nb = (NN + 1023) / 1024;

    hipMemsetAsync(deg, 0, (size_t)NN * 4, stream);

    // fused prologue: histogram (rank-storing) + weight pre-split
    const int prep_total = ET + NW1 + NW2;
    k_prep<<<(prep_total + 255) / 256, 256, 0, stream>>>(ei, deg, rank, W1, W1h, W1l, W2, W2h, W2l);

    // CSR build (scatter also finalizes offs2)
    k_scan_block<<<nb, 1024, 0, stream>>>(deg, offsets, bsum, NN);
    k_scan_bsums<<<1, 64, 0, stream>>>(bsum, nb);
    k_scatter<<<(ET + 255) / 256, 256, 0, stream>>>(ei, offsets, bsum, rank, srcs, offs2);

    // Layer 1: GEMM + fused logits (128-row tiles), then aggregate
    gemm_fused<256><<<(NN + 127) / 128, 512, 0, stream>>>(x, nullptr, nullptr, W1h, W1l, h1b, als1, ald1, aS1, aD1, NN);
    k_agg1<<<NN / 2, 128, 0, stream>>>(h1b, als1, ald1, offs2, srcs, b1, out1h, out1l);

    // Layer 2: GEMM (pre-split A) + fused logits, then aggregate
    gemm_fused<128><<<(NN + 127) / 128, 512, 0, stream>>>(nullptr, out1h, out1l, W2h, W2l, h2b, als2, ald2, aS2, aD2, NN);
    k_agg2<<<NN / 2, 128, 0, stream>>>(h2b, als2, ald2, offs2, srcs, b2, out);
}